// Round 5
// baseline (1303.630 us; speedup 1.0000x reference)
//
#include <hip/hip_runtime.h>
#include <math.h>

typedef _Float16 h2 __attribute__((ext_vector_type(2)));
typedef _Float16 half4_t __attribute__((ext_vector_type(4)));
typedef float f32x4 __attribute__((ext_vector_type(4)));

__device__ inline h2 uph(unsigned u) { return __builtin_bit_cast(h2, u); }
__device__ inline unsigned pkh(float a, float b) {
    return __builtin_bit_cast(unsigned, __builtin_amdgcn_cvt_pkrtz(a, b));
}
__device__ inline float dot2(unsigned a, unsigned b, float c) {
    return __builtin_amdgcn_fdot2(uph(a), uph(b), c, false);
}
__device__ inline float sigf(float x) { return 1.f / (1.f + expf(-x)); }

// ============================================================================
// MFMA implicit-GEMM 3x3x3 conv, pad=1, relu, packed half2 activations.
// D=32: block = (n,d,8-row h-band), M=256. D=16: block = (n,d), M=256.
// N=16 co per grid.y slab. K = 27 taps x 16-ci chunks (mfma_f32_16x16x16f16).
// Window LDS layout XOR-swizzled (ci-quad rotated by (q+ww+(ww>>2))&3) ->
// conflict-free b64 A-reads, no padding (16 halfs/col). B rows stride 20 +
// (q+co)&3 swizzle. UPP pairs fetched from half-res `up` (fused upsample).
// FUSE: d1c 1x1x1 conv fused into epilogue via 16-lane shfl_xor reduction.
// ============================================================================
template<int CIPR, int UPP, int CO, int D, bool FUSE>
__global__ __launch_bounds__(256) void conv3m(
    const unsigned* __restrict__ up, const unsigned* __restrict__ src,
    const float* __restrict__ wgt, const float* __restrict__ bias,
    unsigned* __restrict__ out,
    const float* __restrict__ w1c, const float* __restrict__ b1c,
    float* __restrict__ out32)
{
    constexpr int NCH  = (CIPR + 7) / 8;
    constexpr int CI   = 2 * CIPR;
    constexpr int SP   = CIPR - UPP;
    constexpr int ROWS = (D == 32) ? 10 : 18;
    constexpr int COLS = (D == 32) ? 34 : 18;
    constexpr int DH   = D / 2;

    __shared__ __align__(16) _Float16 win[3 * ROWS * COLS * 16];
    __shared__ __align__(16) _Float16 bw[27 * 16 * 20];

    const int tid  = threadIdx.x;
    const int lane = tid & 63;
    const int wv   = tid >> 6;
    const int l16  = lane & 15;
    const int quad = lane >> 4;

    int n, d, h0;
    if (D == 32) { h0 = (blockIdx.x & 3) * 8; d = (blockIdx.x >> 2) & 31; n = blockIdx.x >> 7; }
    else         { h0 = 0; d = blockIdx.x & 15; n = blockIdx.x >> 4; }

    const int cob = blockIdx.y * 16;
    const int co  = cob + l16;

    f32x4 acc[4];
    {
        float b0 = (co < CO) ? bias[co] : 0.f;
        for (int i = 0; i < 4; ++i) acc[i] = f32x4{b0, b0, b0, b0};
    }

    const int sp  = tid >> 5;          // pair-in-chunk 0..7
    const int col = tid & 31;

    for (int cib = 0; cib < NCH; ++cib) {
        // ---- stage B (swizzled): logical [tap][co16][ci16] ----
        {
            const int bco = tid >> 4;
            const int bci = tid & 15;
            const int gci = cib * 16 + bci;
            const int gco = cob + bco;
            const int qs  = (((bci >> 2) + bco) & 3) * 4 + (bci & 3);
            for (int tap = 0; tap < 27; ++tap) {
                _Float16 v = (_Float16)0.f;
                if (gco < CO && gci < CI)
                    v = (_Float16)wgt[((size_t)gco * CI + gci) * 27 + tap];
                bw[tap * 320 + bco * 20 + qs] = v;
            }
        }
        // ---- stage A window (swizzled u32 pair writes) ----
        {
            const int p = cib * 8 + sp;
            const bool pok = (p < CIPR);
            const int q = sp >> 1, e = (sp & 1) * 2;
            for (int dp = 0; dp < 3; ++dp) {
                const int zd = d - 1 + dp;
                const bool dok = pok && ((unsigned)zd < (unsigned)D);
                for (int hh = 0; hh < ROWS; ++hh) {
                    const int zh = h0 + hh - 1;
                    const bool ok = dok && ((unsigned)zh < (unsigned)D);
                    const int rowbase = (dp * ROWS + hh) * COLS * 16;
                    if (D == 32 || col < COLS) {
                        unsigned v = 0;
                        const int ww = col, zw = ww - 1;
                        if (ok && (unsigned)zw < (unsigned)D) {
                            if (UPP > 0 && p < UPP)
                                v = up[(((size_t)(n * UPP + p) * DH + (zd >> 1)) * DH + (zh >> 1)) * DH + (zw >> 1)];
                            else
                                v = src[(((size_t)(n * SP + (p - UPP)) * D + zd) * D + zh) * D + zw];
                        }
                        const int qs = ((q + ww + (ww >> 2)) & 3) * 4 + e;
                        *(unsigned*)&win[rowbase + ww * 16 + qs] = v;
                    }
                    if (D == 32 && col < 2) {
                        unsigned v = 0;
                        const int ww = 32 + col, zw = ww - 1;
                        if (ok && zw < D) {
                            if (UPP > 0 && p < UPP)
                                v = up[(((size_t)(n * UPP + p) * DH + (zd >> 1)) * DH + (zh >> 1)) * DH + (zw >> 1)];
                            else
                                v = src[(((size_t)(n * SP + (p - UPP)) * D + zd) * D + zh) * D + zw];
                        }
                        const int qs = ((q + ww + (ww >> 2)) & 3) * 4 + e;
                        *(unsigned*)&win[rowbase + ww * 16 + qs] = v;
                    }
                }
            }
        }
        __syncthreads();

        // ---- 27 taps x 4 m-tiles ----
#pragma unroll
        for (int kd = 0; kd < 3; ++kd)
#pragma unroll
        for (int kh = 0; kh < 3; ++kh)
#pragma unroll
        for (int kw = 0; kw < 3; ++kw) {
            const int tap = (kd * 3 + kh) * 3 + kw;
            const int bqs = ((quad + l16) & 3) * 4;
            half4_t bf = *(const half4_t*)&bw[tap * 320 + l16 * 20 + bqs];
#pragma unroll
            for (int i = 0; i < 4; ++i) {
                const int mt = wv * 4 + i;
                int row, ww;
                if (D == 32) { row = kd * ROWS + (mt >> 1) + kh; ww = (mt & 1) * 16 + l16 + kw; }
                else         { row = kd * ROWS + mt + kh;        ww = l16 + kw; }
                const int qs = ((quad + ww + (ww >> 2)) & 3) * 4;
                half4_t af = *(const half4_t*)&win[(row * COLS + ww) * 16 + qs];
                acc[i] = __builtin_amdgcn_mfma_f32_16x16x16f16(af, bf, acc[i], 0, 0, 0);
            }
        }
        __syncthreads();
    }

    // ---- epilogue (relu; C layout col=l16=co, row=quad*4+r) ----
    if (FUSE) {
        const float wc = w1c[l16];
        const float bb = b1c[0];
#pragma unroll
        for (int i = 0; i < 4; ++i) {
            const int mt = wv * 4 + i;
            const int h = h0 + (mt >> 1);
            const int wb0 = (mt & 1) * 16;
#pragma unroll
            for (int r = 0; r < 4; ++r) {
                float v = fmaxf(acc[i][r], 0.f) * wc;
                v += __shfl_xor(v, 1);
                v += __shfl_xor(v, 2);
                v += __shfl_xor(v, 4);
                v += __shfl_xor(v, 8);
                if (l16 == 0) {
                    const int w = wb0 + quad * 4 + r;
                    out32[(((size_t)n * 32 + d) * 32 + h) * 32 + w] = v + bb;
                }
            }
        }
    } else if (co < CO) {
        _Float16* outh = (_Float16*)out;
#pragma unroll
        for (int i = 0; i < 4; ++i) {
            const int mt = wv * 4 + i;
            int h, wb0;
            if (D == 32) { h = h0 + (mt >> 1); wb0 = (mt & 1) * 16; }
            else         { h = mt;             wb0 = 0; }
#pragma unroll
            for (int r = 0; r < 4; ++r) {
                const int w = wb0 + quad * 4 + r;
                float v = fmaxf(acc[i][r], 0.f);
                size_t idx = ((((size_t)(n * (CO / 2) + (co >> 1)) * D + d) * D + h) * D + w) * 2 + (co & 1);
                outh[idx] = (_Float16)v;
            }
        }
    }
}

// e1a: 1 fp32 input channel -> 16 channels (8 pairs packed), D=32
__global__ __launch_bounds__(256) void conv3e1a(
    const float* __restrict__ src, const float* __restrict__ wgt,
    const float* __restrict__ bias, unsigned* __restrict__ out)
{
    __shared__ float sw[27 * 16];
    const int tid = threadIdx.x;
    const int wq = tid % 8;
    const int h  = (tid / 8) % 32;
    const int w0 = wq * 4;
    const int n  = blockIdx.x / 32;
    const int d  = blockIdx.x % 32;

    for (int t = tid; t < 27 * 16; t += 256) {
        int co = t % 16, tap = t / 16;
        sw[t] = wgt[(size_t)co * 27 + tap];
    }
    __syncthreads();

    float acc[16][4];
#pragma unroll
    for (int co = 0; co < 16; ++co) {
        float b0 = bias[co];
        acc[co][0] = b0; acc[co][1] = b0; acc[co][2] = b0; acc[co][3] = b0;
    }

#pragma unroll
    for (int kd = 0; kd < 3; ++kd) {
        int zd = d + kd - 1;
        if ((unsigned)zd >= 32u) continue;
#pragma unroll
        for (int kh = 0; kh < 3; ++kh) {
            int zh = h + kh - 1;
            if ((unsigned)zh >= 32u) continue;
            const float* p = src + ((size_t)n * 32 + zd) * 1024 + zh * 32;
            float v[6];
#pragma unroll
            for (int j = 0; j < 6; ++j) {
                int zw = w0 - 1 + j;
                v[j] = ((unsigned)zw < 32u) ? p[zw] : 0.f;
            }
            const float* swp = &sw[(kd * 9 + kh * 3) * 16];
#pragma unroll
            for (int kw = 0; kw < 3; ++kw)
#pragma unroll
                for (int co = 0; co < 16; ++co)
#pragma unroll
                    for (int j = 0; j < 4; ++j)
                        acc[co][j] = fmaf(v[kw + j], swp[kw * 16 + co], acc[co][j]);
        }
    }

#pragma unroll
    for (int cp = 0; cp < 8; ++cp) {
        unsigned r[4];
#pragma unroll
        for (int j = 0; j < 4; ++j)
            r[j] = pkh(fmaxf(acc[2 * cp][j], 0.f), fmaxf(acc[2 * cp + 1][j], 0.f));
        unsigned* op = out + ((size_t)(n * 8 + cp) * 32 + d) * 1024 + h * 32 + w0;
        *reinterpret_cast<uint4*>(op) = make_uint4(r[0], r[1], r[2], r[3]);
    }
}

// 2x2x2 maxpool on packed half2 arrays
__global__ __launch_bounds__(256) void maxpoolh(
    const unsigned* __restrict__ in, unsigned* __restrict__ out, int total, int Do)
{
    int t = blockIdx.x * blockDim.x + threadIdx.x;
    if (t >= total) return;
    int w = t % Do; int r = t / Do;
    int h = r % Do; r /= Do;
    int d = r % Do; int nc = r / Do;
    int Di = Do * 2;
    const unsigned* p = in + (((size_t)nc * Di + 2 * d) * Di + 2 * h) * Di + 2 * w;
    float m0 = -1e30f, m1 = -1e30f;
#pragma unroll
    for (int a = 0; a < 2; ++a)
#pragma unroll
        for (int b = 0; b < 2; ++b)
#pragma unroll
            for (int c = 0; c < 2; ++c) {
                h2 x = uph(p[((size_t)a * Di + b) * Di + c]);
                m0 = fmaxf(m0, (float)x.x);
                m1 = fmaxf(m1, (float)x.y);
            }
    out[t] = pkh(m0, m1);
}

// ============================================================================
// Fused leaf: iou = conv(xp2_node, w_iou); LSTM apply with fp32 c0.
// Block = one leaf node (16 blocks). Thread owns spatial s=tid and s+256.
// ============================================================================
__global__ __launch_bounds__(256) void treeleaf(
    const unsigned* __restrict__ xp2, const float* __restrict__ w_iou,
    const float* __restrict__ b_iou, const float* __restrict__ c0,
    unsigned* __restrict__ h_all, unsigned* __restrict__ c_all)
{
    __shared__ unsigned xin[10 * 512];
    __shared__ unsigned wb[10 * 27 * 30];
    const int tid = threadIdx.x;
    const int node = 15 + blockIdx.x;

    for (int t = tid; t < 5120; t += 256) xin[t] = xp2[(size_t)node * 5120 + t];
    for (int t = tid; t < 8100; t += 256) {
        int cw = t % 30, r = t / 30, tap = r % 27, cip = r / 27;
        wb[t] = pkh(w_iou[((size_t)cw * 20 + 2 * cip) * 27 + tap],
                    w_iou[((size_t)cw * 20 + 2 * cip + 1) * 27 + tap]);
    }
    __syncthreads();

    const int w = tid & 7, h = (tid >> 3) & 7, d0 = tid >> 6;
    float acc[30][2];
    for (int c = 0; c < 30; ++c) acc[c][0] = acc[c][1] = 0.f;

    for (int kd = 0; kd < 3; ++kd)
    for (int kh = 0; kh < 3; ++kh)
    for (int kw = 0; kw < 3; ++kw) {
        const int tap = (kd * 3 + kh) * 3 + kw;
        const int zh = h + kh - 1, zw = w + kw - 1;
        if ((unsigned)zh >= 8u || (unsigned)zw >= 8u) continue;
        const int zd0 = d0 + kd - 1, zd1 = zd0 + 4;
        const bool ok0 = (unsigned)zd0 < 8u, ok1 = (unsigned)zd1 < 8u;
        const int o0 = zd0 * 64 + zh * 8 + zw;
        for (int cip = 0; cip < 10; ++cip) {
            const unsigned a0 = ok0 ? xin[cip * 512 + o0] : 0u;
            const unsigned a1 = ok1 ? xin[cip * 512 + o0 + 256] : 0u;
            const unsigned* wp = &wb[(cip * 27 + tap) * 30];
#pragma unroll
            for (int cw2 = 0; cw2 < 30; ++cw2) {
                acc[cw2][0] = dot2(a0, wp[cw2], acc[cw2][0]);
                acc[cw2][1] = dot2(a1, wp[cw2], acc[cw2][1]);
            }
        }
    }

    for (int sl = 0; sl < 2; ++sl) {
        const int ss = tid + sl * 256;
        for (int q = 0; q < 5; ++q) {
            float hn[2], cn[2];
#pragma unroll
            for (int e = 0; e < 2; ++e) {
                const int ch = 2 * q + e;
                float iv = acc[ch][sl]      + b_iou[(size_t)ch * 512 + ss];
                float ov = acc[10 + ch][sl] + b_iou[(size_t)(10 + ch) * 512 + ss];
                float uv = acc[20 + ch][sl] + b_iou[(size_t)(20 + ch) * 512 + ss];
                float cin = c0[((size_t)node * 10 + ch) * 512 + ss];
                cn[e] = sigf(iv) * tanhf(uv) + cin;
                hn[e] = sigf(ov) * tanhf(cn[e]);
            }
            h_all[(size_t)node * 2560 + q * 512 + ss] = pkh(hn[0], hn[1]);
            c_all[(size_t)node * 2560 + q * 512 + ss] = pkh(cn[0], cn[1]);
        }
    }
}

// ============================================================================
// Fused internal tree level: per parent node (1 block):
// f = sigmoid(conv(h_child, u_f)); cred = sum f*c_child; hsum = sum h_child;
// iou = conv(hsum, u_iou); LSTM apply.
// ============================================================================
__global__ __launch_bounds__(256) void treelevel(
    const float* __restrict__ u_f, const float* __restrict__ u_iou,
    const float* __restrict__ b_iou,
    unsigned* __restrict__ h_all, unsigned* __restrict__ c_all,
    int pb, int cb)
{
    __shared__ unsigned hch[2 * 5 * 512];
    __shared__ unsigned hs[5 * 512];
    __shared__ unsigned wb[5 * 27 * 30];
    const int tid = threadIdx.x;
    const int node = pb + blockIdx.x;
    const int c0n = cb + 2 * blockIdx.x;

    for (int t = tid; t < 5120; t += 256) hch[t] = h_all[(size_t)c0n * 2560 + t];
    for (int t = tid; t < 1350; t += 256) {
        int cw = t % 10, r = t / 10, tap = r % 27, cip = r / 27;
        wb[t] = pkh(u_f[((size_t)cw * 10 + 2 * cip) * 27 + tap],
                    u_f[((size_t)cw * 10 + 2 * cip + 1) * 27 + tap]);
    }
    __syncthreads();

    const int w = tid & 7, h = (tid >> 3) & 7, d0 = tid >> 6;
    float cred[10][2];
    for (int c = 0; c < 10; ++c) cred[c][0] = cred[c][1] = 0.f;

    for (int ch = 0; ch < 2; ++ch) {
        float facc[10][2];
        for (int c = 0; c < 10; ++c) facc[c][0] = facc[c][1] = 0.f;
        for (int kd = 0; kd < 3; ++kd)
        for (int kh = 0; kh < 3; ++kh)
        for (int kw = 0; kw < 3; ++kw) {
            const int tap = (kd * 3 + kh) * 3 + kw;
            const int zh = h + kh - 1, zw = w + kw - 1;
            if ((unsigned)zh >= 8u || (unsigned)zw >= 8u) continue;
            const int zd0 = d0 + kd - 1, zd1 = zd0 + 4;
            const bool ok0 = (unsigned)zd0 < 8u, ok1 = (unsigned)zd1 < 8u;
            const int o0 = zd0 * 64 + zh * 8 + zw;
            for (int cip = 0; cip < 5; ++cip) {
                const unsigned a0 = ok0 ? hch[ch * 2560 + cip * 512 + o0] : 0u;
                const unsigned a1 = ok1 ? hch[ch * 2560 + cip * 512 + o0 + 256] : 0u;
                const unsigned* wp = &wb[(cip * 27 + tap) * 10];
#pragma unroll
                for (int cw2 = 0; cw2 < 10; ++cw2) {
                    facc[cw2][0] = dot2(a0, wp[cw2], facc[cw2][0]);
                    facc[cw2][1] = dot2(a1, wp[cw2], facc[cw2][1]);
                }
            }
        }
        for (int sl = 0; sl < 2; ++sl) {
            const int ss = tid + sl * 256;
            for (int q = 0; q < 5; ++q) {
                h2 cv = uph(c_all[(size_t)(c0n + ch) * 2560 + q * 512 + ss]);
                cred[2 * q][sl]     += sigf(facc[2 * q][sl])     * (float)cv.x;
                cred[2 * q + 1][sl] += sigf(facc[2 * q + 1][sl]) * (float)cv.y;
            }
        }
    }
    for (int sl = 0; sl < 2; ++sl) {
        const int ss = tid + sl * 256;
        for (int q = 0; q < 5; ++q) {
            h2 a = uph(hch[q * 512 + ss]);
            h2 b = uph(hch[2560 + q * 512 + ss]);
            hs[q * 512 + ss] = pkh((float)a.x + (float)b.x, (float)a.y + (float)b.y);
        }
    }
    __syncthreads();
    for (int t = tid; t < 4050; t += 256) {
        int cw = t % 30, r = t / 30, tap = r % 27, cip = r / 27;
        wb[t] = pkh(u_iou[((size_t)cw * 10 + 2 * cip) * 27 + tap],
                    u_iou[((size_t)cw * 10 + 2 * cip + 1) * 27 + tap]);
    }
    __syncthreads();

    float iou[30][2];
    for (int c = 0; c < 30; ++c) iou[c][0] = iou[c][1] = 0.f;
    for (int kd = 0; kd < 3; ++kd)
    for (int kh = 0; kh < 3; ++kh)
    for (int kw = 0; kw < 3; ++kw) {
        const int tap = (kd * 3 + kh) * 3 + kw;
        const int zh = h + kh - 1, zw = w + kw - 1;
        if ((unsigned)zh >= 8u || (unsigned)zw >= 8u) continue;
        const int zd0 = d0 + kd - 1, zd1 = zd0 + 4;
        const bool ok0 = (unsigned)zd0 < 8u, ok1 = (unsigned)zd1 < 8u;
        const int o0 = zd0 * 64 + zh * 8 + zw;
        for (int cip = 0; cip < 5; ++cip) {
            const unsigned a0 = ok0 ? hs[cip * 512 + o0] : 0u;
            const unsigned a1 = ok1 ? hs[cip * 512 + o0 + 256] : 0u;
            const unsigned* wp = &wb[(cip * 27 + tap) * 30];
#pragma unroll
            for (int cw2 = 0; cw2 < 30; ++cw2) {
                iou[cw2][0] = dot2(a0, wp[cw2], iou[cw2][0]);
                iou[cw2][1] = dot2(a1, wp[cw2], iou[cw2][1]);
            }
        }
    }

    for (int sl = 0; sl < 2; ++sl) {
        const int ss = tid + sl * 256;
        for (int q = 0; q < 5; ++q) {
            float hn[2], cn[2];
#pragma unroll
            for (int e = 0; e < 2; ++e) {
                const int ch = 2 * q + e;
                float iv = iou[ch][sl]      + b_iou[(size_t)ch * 512 + ss];
                float ov = iou[10 + ch][sl] + b_iou[(size_t)(10 + ch) * 512 + ss];
                float uv = iou[20 + ch][sl] + b_iou[(size_t)(20 + ch) * 512 + ss];
                cn[e] = sigf(iv) * tanhf(uv) + cred[ch][sl];
                hn[e] = sigf(ov) * tanhf(cn[e]);
            }
            h_all[(size_t)node * 2560 + q * 512 + ss] = pkh(hn[0], hn[1]);
            c_all[(size_t)node * 2560 + q * 512 + ss] = pkh(cn[0], cn[1]);
        }
    }
}

extern "C" void kernel_launch(void* const* d_in, const int* in_sizes, int n_in,
                              void* d_out, int out_size, void* d_ws, size_t ws_size,
                              hipStream_t stream)
{
    const float* data  = (const float*)d_in[0];
    const float* c0    = (const float*)d_in[2];
    const float* e1a_w = (const float*)d_in[3];  const float* e1a_b = (const float*)d_in[4];
    const float* e1b_w = (const float*)d_in[5];  const float* e1b_b = (const float*)d_in[6];
    const float* e2a_w = (const float*)d_in[7];  const float* e2a_b = (const float*)d_in[8];
    const float* e2b_w = (const float*)d_in[9];  const float* e2b_b = (const float*)d_in[10];
    const float* d2a_w = (const float*)d_in[11]; const float* d2a_b = (const float*)d_in[12];
    const float* d2b_w = (const float*)d_in[13]; const float* d2b_b = (const float*)d_in[14];
    const float* d1a_w = (const float*)d_in[15]; const float* d1a_b = (const float*)d_in[16];
    const float* d1b_w = (const float*)d_in[17]; const float* d1b_b = (const float*)d_in[18];
    const float* d1c_w = (const float*)d_in[19]; const float* d1c_b = (const float*)d_in[20];
    const float* w_iou = (const float*)d_in[21];
    const float* u_iou = (const float*)d_in[22];
    const float* u_f   = (const float*)d_in[23];
    const float* b_iou = (const float*)d_in[24];

    unsigned* ws = (unsigned*)d_ws;
    size_t o = 0;
    unsigned* t1   = ws + o; o += 8126464;   // [31,8p,32^3]  (reused as t4)
    unsigned* x0   = ws + o; o += 8126464;   // [31,8p,32^3]
    unsigned* xp   = ws + o; o += 1015808;   // [31,8p,16^3]
    unsigned* t2   = ws + o; o += 2031616;   // [31,16p,16^3] (reused as t3 [31,10p,16^3])
    unsigned* x1   = ws + o; o += 1269760;   // [31,10p,16^3]
    unsigned* xp2  = ws + o; o += 158720;    // [31,10p,8^3]
    unsigned* h_all= ws + o; o += 79360;     // [31,5p,8^3]
    unsigned* c_all= ws + o; o += 79360;
    unsigned* y2   = ws + o; o += 2031616;   // [31,16p,16^3]
    unsigned* t3 = t2;
    unsigned* t4 = t1;
    (void)ws_size; (void)in_sizes; (void)n_in; (void)out_size;

    dim3 b256(256);

    // ---- Encoder ----
    conv3e1a<<<dim3(31 * 32), b256, 0, stream>>>(data, e1a_w, e1a_b, t1);
    conv3m<8, 0, 16, 32, false><<<dim3(3968, 1), b256, 0, stream>>>(
        nullptr, t1, e1b_w, e1b_b, x0, nullptr, nullptr, nullptr);
    maxpoolh<<<dim3((1015808 + 255) / 256), b256, 0, stream>>>(x0, xp, 1015808, 16);
    conv3m<8, 0, 32, 16, false><<<dim3(496, 2), b256, 0, stream>>>(
        nullptr, xp, e2a_w, e2a_b, t2, nullptr, nullptr, nullptr);
    conv3m<16, 0, 20, 16, false><<<dim3(496, 2), b256, 0, stream>>>(
        nullptr, t2, e2b_w, e2b_b, x1, nullptr, nullptr, nullptr);
    maxpoolh<<<dim3((158720 + 255) / 256), b256, 0, stream>>>(x1, xp2, 158720, 8);

    // ---- Tree ----
    treeleaf<<<dim3(16), b256, 0, stream>>>(xp2, w_iou, b_iou, c0, h_all, c_all);
    for (int lvl = 3; lvl >= 0; --lvl) {
        int P  = 1 << lvl;
        treelevel<<<dim3(P), b256, 0, stream>>>(
            u_f, u_iou, b_iou, h_all, c_all, P - 1, 2 * P - 1);
    }

    // ---- Decoder ----
    conv3m<15, 5, 20, 16, false><<<dim3(496, 2), b256, 0, stream>>>(
        h_all, x1, d2a_w, d2a_b, t3, nullptr, nullptr, nullptr);
    conv3m<10, 0, 32, 16, false><<<dim3(496, 2), b256, 0, stream>>>(
        nullptr, t3, d2b_w, d2b_b, y2, nullptr, nullptr, nullptr);
    conv3m<24, 16, 16, 32, false><<<dim3(3968, 1), b256, 0, stream>>>(
        y2, x0, d1a_w, d1a_b, t4, nullptr, nullptr, nullptr);
    conv3m<8, 0, 16, 32, true><<<dim3(3968, 1), b256, 0, stream>>>(
        nullptr, t4, d1b_w, d1b_b, nullptr, d1c_w, d1c_b, (float*)d_out);
}